// Round 4
// baseline (713.369 us; speedup 1.0000x reference)
//
#include <hip/hip_runtime.h>

// Problem constants (from reference setup_inputs):
//   x: (4,4096,1024) fp32 -> M=16384, dim=1024, hidden=4096, rank=16
//   w_fc: (4096,1024), w_proj: (1024,4096), u:(4096,16), v:(16,1024), fast_b:(16,16), gate scalar
// out: (16384,1024) fp32
//
// R1: XOR-swizzled LDS -> conflicts 1.68e7 -> 0 (time-neutral).
// R2: dbuf + vmcnt(4) prefetch -> 196 -> 189 us/gemm (small).
// R3: AITER-style restructure: B (weights) loads DIRECT to registers from global
//     (L2-hot, no LDS round-trip); A-only LDS dbuf with BK=64 -> 32 MFMA per
//     barrier-pair; raw s_barrier + s_waitcnt vmcnt(12) keeps next tile's loads
//     in flight across the barrier.

typedef unsigned short u16;
typedef __attribute__((ext_vector_type(8))) short short8;
typedef __attribute__((ext_vector_type(4))) float float4v;

#define M_TOK   16384
#define DIM     1024
#define HID     4096

// ---------- helpers ----------

__device__ __forceinline__ u16 f2bf(float f) {
    union { float f; unsigned u; } v; v.f = f;
    unsigned r = v.u + 0x7fffu + ((v.u >> 16) & 1u);   // RNE
    return (u16)(r >> 16);
}

__device__ __forceinline__ void gload_lds16(const u16* g, u16* l) {
    __builtin_amdgcn_global_load_lds(
        (const __attribute__((address_space(1))) void*)g,
        (__attribute__((address_space(3))) void*)l, 16, 0, 0);
}

// ---------- prologue kernels ----------

__global__ __launch_bounds__(256) void cvt_x_kernel(const float* __restrict__ x,
                                                    u16* __restrict__ y) {
    int i = (blockIdx.x * 256 + threadIdx.x) * 4;
    float4 v = *reinterpret_cast<const float4*>(x + i);
    ushort4 o;
    o.x = f2bf(v.x); o.y = f2bf(v.y); o.z = f2bf(v.z); o.w = f2bf(v.w);
    *reinterpret_cast<ushort4*>(y + i) = o;
}

__global__ __launch_bounds__(256) void adapter_T_kernel(const float* __restrict__ u,
                                                        const float* __restrict__ fb,
                                                        float* __restrict__ T) {
    int i = blockIdx.x * 256 + threadIdx.x;
    int row = i >> 4, r = i & 15;
    float s = 0.f;
#pragma unroll
    for (int k = 0; k < 16; k++) s += u[row * 16 + k] * fb[k * 16 + r];
    T[i] = s;
}

__global__ __launch_bounds__(256) void build_w1_kernel(const float* __restrict__ w,
                                                       const float* __restrict__ T,
                                                       const float* __restrict__ v,
                                                       const float* __restrict__ gate,
                                                       u16* __restrict__ W1) {
    const int row = blockIdx.x, tid = threadIdx.x;
    float s = 0.f;
#pragma unroll
    for (int jj = 0; jj < 4; jj++) s += fabsf(w[row * 1024 + tid + jj * 256]);
#pragma unroll
    for (int o = 32; o > 0; o >>= 1) s += __shfl_down(s, o, 64);
    __shared__ float red[4];
    if ((tid & 63) == 0) red[tid >> 6] = s;
    __syncthreads();
    const float scale = fmaxf((red[0] + red[1] + red[2] + red[3]) * (1.f / 1024.f), 1e-5f);
    const float g = gate[0];
    float t[16];
#pragma unroll
    for (int r = 0; r < 16; r++) t[r] = T[row * 16 + r];
#pragma unroll
    for (int jj = 0; jj < 4; jj++) {
        const int j = tid + jj * 256;
        const float wv = w[row * 1024 + j];
        float tern = rintf(wv / scale);
        tern = fminf(1.f, fmaxf(-1.f, tern));
        float ad = 0.f;
#pragma unroll
        for (int r = 0; r < 16; r++) ad += t[r] * v[r * 1024 + j];
        W1[row * 1024 + j] = f2bf(tern * scale + g * ad);
    }
}

__global__ __launch_bounds__(256) void build_w2_kernel(const float* __restrict__ w,
                                                       u16* __restrict__ W2) {
    const int row = blockIdx.x, tid = threadIdx.x;
    float s = 0.f;
#pragma unroll
    for (int jj = 0; jj < 16; jj++) s += fabsf(w[row * 4096 + tid + jj * 256]);
#pragma unroll
    for (int o = 32; o > 0; o >>= 1) s += __shfl_down(s, o, 64);
    __shared__ float red[4];
    if ((tid & 63) == 0) red[tid >> 6] = s;
    __syncthreads();
    const float scale = fmaxf((red[0] + red[1] + red[2] + red[3]) * (1.f / 4096.f), 1e-5f);
#pragma unroll
    for (int jj = 0; jj < 16; jj++) {
        const int j = tid + jj * 256;
        float tern = rintf(w[row * 4096 + j] / scale);
        tern = fminf(1.f, fmaxf(-1.f, tern));
        W2[row * 4096 + j] = f2bf(tern * scale);
    }
}

// ---------- GEMM: C[M,N] = A[M,K] @ B[N,K]^T (both bf16 row-major) ----------
// 128x128 block, 4 waves each 64x64. BK=64 (2 mfma-K-steps per barrier section).
// A: LDS double-buffer via global_load_lds (XOR-swizzled, conflict-free).
//    chunk c (0..1023): row=c>>3, pos=c&7 holds k-chunk (c&7)^((c>>3)&7).
// B: direct global->register fragment loads, ping-pong prefetch (L2-hot weights).
// K-loop body: issue A(k+1)->LDS + B(k+1)->regs, s_waitcnt vmcnt(12),
//              s_barrier, compute(k), s_barrier.
// EPI 0: relu(v)^2 -> bf16 store.  EPI 1: fp32 store.
template <int N, int K, int EPI>
__global__ __launch_bounds__(256, 2) void gemm_bt(const u16* __restrict__ A,
                                                  const u16* __restrict__ B,
                                                  void* __restrict__ Cv) {
    __shared__ alignas(16) u16 As[2][128 * 64];
    const int tid = threadIdx.x;
    const int bn = blockIdx.x, bm = blockIdx.y;
    const int wave = tid >> 6, lane = tid & 63;
    const int wm = (wave >> 1) << 6;
    const int wn = (wave & 1) << 6;
    const int lr = lane & 15, quad = lane >> 4;

    float4v acc[4][4];
#pragma unroll
    for (int i = 0; i < 4; i++)
#pragma unroll
        for (int j = 0; j < 4; j++) acc[i][j] = (float4v)0.0f;

    // A staging setup (4 chunks/thread)
    const u16* Ag[4];
    u16* Al[2][4];
#pragma unroll
    for (int c = 0; c < 4; c++) {
        const int ci = tid + c * 256;
        const int row = ci >> 3, p = ci & 7;
        const int kc = p ^ (row & 7);
        Ag[c] = A + (size_t)(bm * 128 + row) * K + kc * 8;
        Al[0][c] = &As[0][ci * 8];
        Al[1][c] = &As[1][ci * 8];
    }

    // B direct-fragment bases: row = bn*128+wn+lr+16j, k offset quad*8
    const u16* Bg[4];
#pragma unroll
    for (int j = 0; j < 4; j++)
        Bg[j] = B + (size_t)(bn * 128 + wn + lr + 16 * j) * K + quad * 8;

    // A fragment LDS elem offsets: row' = wm+lr+16i, pos = (4*ks+quad)^(lr&7)
    int offA[4][2];
#pragma unroll
    for (int i = 0; i < 4; i++)
#pragma unroll
        for (int ks = 0; ks < 2; ks++)
            offA[i][ks] = (wm + lr + 16 * i) * 64 + (((4 * ks + quad) ^ (lr & 7)) * 8);

    short8 Bc[2][4], Bn[2][4];
    constexpr int NIT = K / 64;   // 16 (gemm1) / 64 (gemm2), both even

#define ISSUE_A(k_, buf_)                                          \
    do {                                                           \
        _Pragma("unroll") for (int c = 0; c < 4; c++)              \
            gload_lds16(Ag[c] + (k_) * 64, Al[buf_][c]);           \
    } while (0)

#define ISSUE_B(k_, DST)                                                       \
    do {                                                                       \
        _Pragma("unroll") for (int ks = 0; ks < 2; ks++)                       \
            _Pragma("unroll") for (int j = 0; j < 4; j++)                      \
                DST[ks][j] = *reinterpret_cast<const short8*>(                 \
                    Bg[j] + (k_) * 64 + ks * 32);                              \
    } while (0)

#define COMPUTE(buf_, BR)                                                      \
    do {                                                                       \
        const u16* base_ = As[buf_];                                           \
        _Pragma("unroll") for (int ks = 0; ks < 2; ks++) {                     \
            short8 af[4];                                                      \
            _Pragma("unroll") for (int i = 0; i < 4; i++)                      \
                af[i] = *reinterpret_cast<const short8*>(base_ + offA[i][ks]); \
            _Pragma("unroll") for (int i = 0; i < 4; i++)                      \
                _Pragma("unroll") for (int j = 0; j < 4; j++)                  \
                    acc[i][j] = __builtin_amdgcn_mfma_f32_16x16x32_bf16(       \
                        af[i], BR[ks][j], acc[i][j], 0, 0, 0);                 \
        }                                                                      \
    } while (0)

#define BODY(k_, buf_, CUR, NXT)                                   \
    do {                                                           \
        if ((k_) + 1 < NIT) {                                      \
            ISSUE_A((k_) + 1, (buf_) ^ 1);                         \
            ISSUE_B((k_) + 1, NXT);                                \
            asm volatile("s_waitcnt vmcnt(12)" ::: "memory");      \
        } else {                                                   \
            asm volatile("s_waitcnt vmcnt(0)" ::: "memory");       \
        }                                                          \
        __builtin_amdgcn_s_barrier();                              \
        COMPUTE(buf_, CUR);                                        \
        asm volatile("" ::: "memory");                             \
        __builtin_amdgcn_s_barrier();                              \
    } while (0)

    ISSUE_A(0, 0);
    ISSUE_B(0, Bc);
    for (int it = 0; it < NIT; it += 2) {
        BODY(it, 0, Bc, Bn);
        BODY(it + 1, 1, Bn, Bc);
    }

#undef ISSUE_A
#undef ISSUE_B
#undef COMPUTE
#undef BODY

    // C/D layout: col=lane&15, row=quad*4+reg (m89/m91-verified)
    const int row0 = bm * 128 + wm + quad * 4;
    const int col0 = bn * 128 + wn + lr;
#pragma unroll
    for (int i = 0; i < 4; i++)
#pragma unroll
        for (int j = 0; j < 4; j++) {
            const int col = col0 + j * 16;
#pragma unroll
            for (int r = 0; r < 4; r++) {
                const int row = row0 + i * 16 + r;
                const float vv = acc[i][j][r];
                if (EPI == 0) {
                    const float rr = fmaxf(vv, 0.f);
                    ((u16*)Cv)[(size_t)row * N + col] = f2bf(rr * rr);
                } else {
                    ((float*)Cv)[(size_t)row * N + col] = vv;
                }
            }
        }
}

// ---------- launch ----------

extern "C" void kernel_launch(void* const* d_in, const int* in_sizes, int n_in,
                              void* d_out, int out_size, void* d_ws, size_t ws_size,
                              hipStream_t stream) {
    const float* x      = (const float*)d_in[0];
    const float* fast_b = (const float*)d_in[1];
    const float* w_fc   = (const float*)d_in[2];
    const float* w_proj = (const float*)d_in[3];
    const float* u      = (const float*)d_in[4];
    const float* v      = (const float*)d_in[5];
    const float* gate   = (const float*)d_in[6];
    float* out = (float*)d_out;

    char* ws = (char*)d_ws;
    u16*   Xb  = (u16*)(ws + 0);                         // 16384*1024*2 = 32 MB
    u16*   W1  = (u16*)(ws + 33554432);                  // 4096*1024*2  =  8 MB
    u16*   W2  = (u16*)(ws + 41943040);                  // 1024*4096*2  =  8 MB
    u16*   RSQ = (u16*)(ws + 50331648);                  // 16384*4096*2 = 128 MB
    float* T   = (float*)(ws + 184549376);               // 4096*16*4    = 256 KB

    cvt_x_kernel<<<M_TOK * DIM / (256 * 4), 256, 0, stream>>>(x, Xb);
    adapter_T_kernel<<<HID * 16 / 256, 256, 0, stream>>>(u, fast_b, T);
    build_w1_kernel<<<HID, 256, 0, stream>>>(w_fc, T, v, gate, W1);
    build_w2_kernel<<<DIM, 256, 0, stream>>>(w_proj, W2);

    // GEMM1: (16384,1024) @ (4096,1024)^T -> relu^2 bf16 (16384,4096)
    gemm_bt<HID, DIM, 0><<<dim3(HID / 128, M_TOK / 128), 256, 0, stream>>>(Xb, W1, RSQ);
    // GEMM2: (16384,4096) @ (1024,4096)^T -> fp32 out (16384,1024)
    gemm_bt<DIM, HID, 1><<<dim3(DIM / 128, M_TOK / 128), 256, 0, stream>>>(RSQ, W2, out);
}

// Round 5
// 459.115 us; speedup vs baseline: 1.5538x; 1.5538x over previous
//
#include <hip/hip_runtime.h>

// Problem constants (from reference setup_inputs):
//   x: (4,4096,1024) fp32 -> M=16384, dim=1024, hidden=4096, rank=16
//   w_fc: (4096,1024), w_proj: (1024,4096), u:(4096,16), v:(16,1024), fast_b:(16,16), gate scalar
// out: (16384,1024) fp32
//
// R1: XOR-swizzled LDS -> conflicts 1.68e7 -> 0 (time-neutral).
// R2: dbuf + vmcnt(4) prefetch -> 196 -> 189 us/gemm (small).
// R3/R4: B direct-to-register gather -> REGRESSED (300 us/gemm; occupancy + VMEM
//        return-path). Reverted.
// R5: BK=64 single-buffered (32 KB LDS, A+B via global_load_lds), 32 MFMA per
//     barrier-pair (2x R2), full 128B-segment coalescing via XOR chunk permute.
//     Halves barrier count; keeps VGPR~60 so 4 waves/SIMD co-residency hides drain.

typedef unsigned short u16;
typedef __attribute__((ext_vector_type(8))) short short8;
typedef __attribute__((ext_vector_type(4))) float float4v;

#define M_TOK   16384
#define DIM     1024
#define HID     4096

// ---------- helpers ----------

__device__ __forceinline__ u16 f2bf(float f) {
    union { float f; unsigned u; } v; v.f = f;
    unsigned r = v.u + 0x7fffu + ((v.u >> 16) & 1u);   // RNE
    return (u16)(r >> 16);
}

__device__ __forceinline__ void gload_lds16(const u16* g, u16* l) {
    __builtin_amdgcn_global_load_lds(
        (const __attribute__((address_space(1))) void*)g,
        (__attribute__((address_space(3))) void*)l, 16, 0, 0);
}

// ---------- prologue kernels ----------

__global__ __launch_bounds__(256) void cvt_x_kernel(const float* __restrict__ x,
                                                    u16* __restrict__ y) {
    int i = (blockIdx.x * 256 + threadIdx.x) * 4;
    float4 v = *reinterpret_cast<const float4*>(x + i);
    ushort4 o;
    o.x = f2bf(v.x); o.y = f2bf(v.y); o.z = f2bf(v.z); o.w = f2bf(v.w);
    *reinterpret_cast<ushort4*>(y + i) = o;
}

__global__ __launch_bounds__(256) void adapter_T_kernel(const float* __restrict__ u,
                                                        const float* __restrict__ fb,
                                                        float* __restrict__ T) {
    int i = blockIdx.x * 256 + threadIdx.x;
    int row = i >> 4, r = i & 15;
    float s = 0.f;
#pragma unroll
    for (int k = 0; k < 16; k++) s += u[row * 16 + k] * fb[k * 16 + r];
    T[i] = s;
}

__global__ __launch_bounds__(256) void build_w1_kernel(const float* __restrict__ w,
                                                       const float* __restrict__ T,
                                                       const float* __restrict__ v,
                                                       const float* __restrict__ gate,
                                                       u16* __restrict__ W1) {
    const int row = blockIdx.x, tid = threadIdx.x;
    float s = 0.f;
#pragma unroll
    for (int jj = 0; jj < 4; jj++) s += fabsf(w[row * 1024 + tid + jj * 256]);
#pragma unroll
    for (int o = 32; o > 0; o >>= 1) s += __shfl_down(s, o, 64);
    __shared__ float red[4];
    if ((tid & 63) == 0) red[tid >> 6] = s;
    __syncthreads();
    const float scale = fmaxf((red[0] + red[1] + red[2] + red[3]) * (1.f / 1024.f), 1e-5f);
    const float g = gate[0];
    float t[16];
#pragma unroll
    for (int r = 0; r < 16; r++) t[r] = T[row * 16 + r];
#pragma unroll
    for (int jj = 0; jj < 4; jj++) {
        const int j = tid + jj * 256;
        const float wv = w[row * 1024 + j];
        float tern = rintf(wv / scale);
        tern = fminf(1.f, fmaxf(-1.f, tern));
        float ad = 0.f;
#pragma unroll
        for (int r = 0; r < 16; r++) ad += t[r] * v[r * 1024 + j];
        W1[row * 1024 + j] = f2bf(tern * scale + g * ad);
    }
}

__global__ __launch_bounds__(256) void build_w2_kernel(const float* __restrict__ w,
                                                       u16* __restrict__ W2) {
    const int row = blockIdx.x, tid = threadIdx.x;
    float s = 0.f;
#pragma unroll
    for (int jj = 0; jj < 16; jj++) s += fabsf(w[row * 4096 + tid + jj * 256]);
#pragma unroll
    for (int o = 32; o > 0; o >>= 1) s += __shfl_down(s, o, 64);
    __shared__ float red[4];
    if ((tid & 63) == 0) red[tid >> 6] = s;
    __syncthreads();
    const float scale = fmaxf((red[0] + red[1] + red[2] + red[3]) * (1.f / 4096.f), 1e-5f);
#pragma unroll
    for (int jj = 0; jj < 16; jj++) {
        const int j = tid + jj * 256;
        float tern = rintf(w[row * 4096 + j] / scale);
        tern = fminf(1.f, fmaxf(-1.f, tern));
        W2[row * 4096 + j] = f2bf(tern * scale);
    }
}

// ---------- GEMM: C[M,N] = A[M,K] @ B[N,K]^T (both bf16 row-major) ----------
// 128x128 block, 4 waves each 64x64. BK=64, single-buffered (32 KB LDS total).
// Chunk q (of 1024 per tile): row=q>>3, pos=q&7; position p of row r holds
// k-chunk p ^ (r&7). Staging instruction = 8 rows x 128B contiguous (coalesced);
// frag ds_read_b128 conflict-free (pos = (4*ks+quad) ^ (lr&7)).
// Per iter: 8 global_load_lds, sync, 2 k-steps x 16 mfma = 32 MFMA/wave, sync.
// EPI 0: relu(v)^2 -> bf16 store.  EPI 1: fp32 store.
template <int N, int K, int EPI>
__global__ __launch_bounds__(256, 2) void gemm_bt(const u16* __restrict__ A,
                                                  const u16* __restrict__ B,
                                                  void* __restrict__ Cv) {
    __shared__ alignas(16) u16 As[128 * 64];
    __shared__ alignas(16) u16 Bs[128 * 64];
    const int tid = threadIdx.x;
    const int bn = blockIdx.x, bm = blockIdx.y;
    const int wave = tid >> 6, lane = tid & 63;
    const int wm = (wave >> 1) << 6;
    const int wn = (wave & 1) << 6;
    const int lr = lane & 15, quad = lane >> 4;

    float4v acc[4][4];
#pragma unroll
    for (int i = 0; i < 4; i++)
#pragma unroll
        for (int j = 0; j < 4; j++) acc[i][j] = (float4v)0.0f;

    // staging setup: 4 chunks/thread per tile
    const u16* Ag[4];
    const u16* Bg[4];
    u16* Al[4];
    u16* Bl[4];
#pragma unroll
    for (int c = 0; c < 4; c++) {
        const int q = tid + c * 256;           // 0..1023
        const int row = q >> 3, p = q & 7;
        const int kc = p ^ (row & 7);
        Ag[c] = A + (size_t)(bm * 128 + row) * K + kc * 8;
        Bg[c] = B + (size_t)(bn * 128 + row) * K + kc * 8;
        Al[c] = As + q * 8;
        Bl[c] = Bs + q * 8;
    }

    // fragment LDS elem offsets: row' = (wm|wn)+lr+16*i, pos = (4*ks+quad)^(lr&7)
    int offA[4][2], offB[4][2];
#pragma unroll
    for (int i = 0; i < 4; i++)
#pragma unroll
        for (int ks = 0; ks < 2; ks++) {
            const int p = ((4 * ks + quad) ^ (lr & 7)) * 8;
            offA[i][ks] = (wm + lr + 16 * i) * 64 + p;
            offB[i][ks] = (wn + lr + 16 * i) * 64 + p;
        }

    for (int k0 = 0; k0 < K; k0 += 64) {
#pragma unroll
        for (int c = 0; c < 4; c++) gload_lds16(Ag[c] + k0, Al[c]);
#pragma unroll
        for (int c = 0; c < 4; c++) gload_lds16(Bg[c] + k0, Bl[c]);
        __syncthreads();
#pragma unroll
        for (int ks = 0; ks < 2; ks++) {
            short8 af[4], bfr[4];
#pragma unroll
            for (int i = 0; i < 4; i++)
                af[i] = *reinterpret_cast<const short8*>(As + offA[i][ks]);
#pragma unroll
            for (int j = 0; j < 4; j++)
                bfr[j] = *reinterpret_cast<const short8*>(Bs + offB[j][ks]);
#pragma unroll
            for (int i = 0; i < 4; i++)
#pragma unroll
                for (int j = 0; j < 4; j++)
                    acc[i][j] = __builtin_amdgcn_mfma_f32_16x16x32_bf16(
                        af[i], bfr[j], acc[i][j], 0, 0, 0);
        }
        __syncthreads();
    }

    // C/D layout: col=lane&15, row=quad*4+reg (m89/m91-verified)
    const int row0 = bm * 128 + wm + quad * 4;
    const int col0 = bn * 128 + wn + lr;
#pragma unroll
    for (int i = 0; i < 4; i++)
#pragma unroll
        for (int j = 0; j < 4; j++) {
            const int col = col0 + j * 16;
#pragma unroll
            for (int r = 0; r < 4; r++) {
                const int row = row0 + i * 16 + r;
                const float vv = acc[i][j][r];
                if (EPI == 0) {
                    const float rr = fmaxf(vv, 0.f);
                    ((u16*)Cv)[(size_t)row * N + col] = f2bf(rr * rr);
                } else {
                    ((float*)Cv)[(size_t)row * N + col] = vv;
                }
            }
        }
}

// ---------- launch ----------

extern "C" void kernel_launch(void* const* d_in, const int* in_sizes, int n_in,
                              void* d_out, int out_size, void* d_ws, size_t ws_size,
                              hipStream_t stream) {
    const float* x      = (const float*)d_in[0];
    const float* fast_b = (const float*)d_in[1];
    const float* w_fc   = (const float*)d_in[2];
    const float* w_proj = (const float*)d_in[3];
    const float* u      = (const float*)d_in[4];
    const float* v      = (const float*)d_in[5];
    const float* gate   = (const float*)d_in[6];
    float* out = (float*)d_out;

    char* ws = (char*)d_ws;
    u16*   Xb  = (u16*)(ws + 0);                         // 16384*1024*2 = 32 MB
    u16*   W1  = (u16*)(ws + 33554432);                  // 4096*1024*2  =  8 MB
    u16*   W2  = (u16*)(ws + 41943040);                  // 1024*4096*2  =  8 MB
    u16*   RSQ = (u16*)(ws + 50331648);                  // 16384*4096*2 = 128 MB
    float* T   = (float*)(ws + 184549376);               // 4096*16*4    = 256 KB

    cvt_x_kernel<<<M_TOK * DIM / (256 * 4), 256, 0, stream>>>(x, Xb);
    adapter_T_kernel<<<HID * 16 / 256, 256, 0, stream>>>(u, fast_b, T);
    build_w1_kernel<<<HID, 256, 0, stream>>>(w_fc, T, v, gate, W1);
    build_w2_kernel<<<DIM, 256, 0, stream>>>(w_proj, W2);

    // GEMM1: (16384,1024) @ (4096,1024)^T -> relu^2 bf16 (16384,4096)
    gemm_bt<HID, DIM, 0><<<dim3(HID / 128, M_TOK / 128), 256, 0, stream>>>(Xb, W1, RSQ);
    // GEMM2: (16384,4096) @ (1024,4096)^T -> fp32 out (16384,1024)
    gemm_bt<DIM, HID, 1><<<dim3(DIM / 128, M_TOK / 128), 256, 0, stream>>>(RSQ, W2, out);
}